// Round 3
// baseline (418.517 us; speedup 1.0000x reference)
//
#include <hip/hip_runtime.h>
#include <hip/hip_bf16.h>
#include <math.h>

#define BB 8
#define HH 128
#define WW 128
#define CC 96
#define NPIX (BB*HH*WW)
#define EPSF 1e-5f
#define FT_SMOOTH_F 1e-5f
#define ROWB 8320                 // 130 px x 64 B per LDS row (fallback path)
#define WELEM 82944               // 864*96 weight elements per conv
#define WBLK 972                  // precast: weight-repack blocks (3*WELEM/256)
#define XJOBS (3*NPIX*12)         // precast: x-cast jobs (8 floats each)

typedef short short8 __attribute__((ext_vector_type(8)));
typedef float f32x4 __attribute__((ext_vector_type(4)));

__device__ __forceinline__ float ftanimoto(float tpl, float tpp, float tll) {
    float num = tpl + FT_SMOOTH_F;
    float denum = 0.0f;
    float a = 1.0f;
#pragma unroll
    for (int d = 0; d < 5; ++d) {
        float bco = -(2.0f * a - 1.0f);
        denum += 1.0f / (a * (tpp + tll) + bco * tpl + FT_SMOOTH_F);
        a *= 2.0f;
    }
    return num * denum * 0.2f;
}

__device__ __forceinline__ unsigned short f2bf(float f) {
    __hip_bfloat16 h = __float2bfloat16(f);
    return *(unsigned short*)&h;
}

__device__ __forceinline__ float bf2f(unsigned short u) {
    return __uint_as_float((unsigned int)u << 16);
}

// ---------------------------------------------------------------------------
// precast: ONE dispatch does (a) weight repack (blocks < WBLK), exactly the
// old cast_wT2, and (b) x1..3 fp32 -> bf16 cast into xb (blocks >= WBLK).
// Fallback mode launches only WBLK blocks (weights only).
// ---------------------------------------------------------------------------
__global__ __launch_bounds__(256) void precast(
    const float* __restrict__ wq, const float* __restrict__ wk,
    const float* __restrict__ wv, unsigned short* __restrict__ wT2,
    const float* __restrict__ x1, const float* __restrict__ x2,
    const float* __restrict__ x3, unsigned short* __restrict__ xb)
{
    if (blockIdx.x < WBLK) {
        const int tid = blockIdx.x * 256 + threadIdx.x;   // < 3*WELEM exactly
        const int cid = tid / WELEM;
        const int o = tid - cid * WELEM;
        const int j = o & 7;
        const int rest = o >> 3;
        const int lq = rest & 63;
        const int lrow = lq >> 2, qq = lq & 3;
        const int tile = rest >> 6;          // (tap*3+cc)*6+nt
        const int nt = tile % 6;
        const int tcc = tile / 6;
        const int cc = tcc % 3, tap = tcc / 3;
        const int ci = cc * 32 + qq * 8 + j;
        const int co = nt * 16 + lrow;
        const float* w = (cid == 0) ? wq : (cid == 1) ? wk : wv;
        wT2[tid] = f2bf(w[(size_t)(tap * CC + ci) * CC + co]);
        return;
    }
    const int tid2 = (blockIdx.x - WBLK) * 256 + threadIdx.x;  // < XJOBS exactly
    const int cid = tid2 / (NPIX * 12);
    const int rem = tid2 - cid * (NPIX * 12);
    const float* xs = (cid == 0) ? x1 : (cid == 1) ? x2 : x3;
    const float4 a0 = *(const float4*)(xs + (size_t)rem * 8);
    const float4 a1 = *(const float4*)(xs + (size_t)rem * 8 + 4);
    short8 o;
    o[0] = (short)f2bf(a0.x); o[1] = (short)f2bf(a0.y);
    o[2] = (short)f2bf(a0.z); o[3] = (short)f2bf(a0.w);
    o[4] = (short)f2bf(a1.x); o[5] = (short)f2bf(a1.y);
    o[6] = (short)f2bf(a1.z); o[7] = (short)f2bf(a1.w);
    *(short8*)(xb + (size_t)cid * NPIX * CC + (size_t)rem * 8) = o;
}

// ---------------------------------------------------------------------------
// Direct-global implicit-GEMM conv: NO LDS, NO barriers. A-fragments (16 B =
// 8 channels of one pixel, bf16) load straight from xb — the natural MFMA A
// layout — and hit L1/L2 (per-CU working set ~33 KB, 9x tap reuse cached).
// B from the repacked wT2 (1 KB contiguous wave loads, L1-resident).
// Latency hidden purely by 12 waves/CU of free-running MFMA.
// ---------------------------------------------------------------------------
__global__ __launch_bounds__(256, 3) void conv_direct(
    const unsigned short* __restrict__ xb, const unsigned short* __restrict__ wT2,
    const float* __restrict__ gq, const float* __restrict__ bq,
    const float* __restrict__ mq, const float* __restrict__ vq,
    const float* __restrict__ gk, const float* __restrict__ bk,
    const float* __restrict__ mk, const float* __restrict__ vk,
    const float* __restrict__ gv, const float* __restrict__ bv,
    const float* __restrict__ mv, const float* __restrict__ vv,
    unsigned short* __restrict__ qb, unsigned short* __restrict__ kb,
    unsigned short* __restrict__ vb)
{
    const int tid = threadIdx.x;
    const int wv = tid >> 6;
    const int L  = tid & 63;
    const int cid = blockIdx.x >> 9;                  // 0:q 1:k 2:v
    const int blk = blockIdx.x & 511;
    const int b  = blk >> 6;
    const int h0 = (blk & 63) << 1;
    const int hrow = h0 + (wv >> 1);
    const int wwbase = (wv & 1) << 6;
    const int lrow = L & 15;
    const int qq = L >> 4;

    const unsigned short* xbc = xb + (size_t)cid * NPIX * CC;
    const unsigned short* wT2p = wT2 + (size_t)cid * WELEM;

    f32x4 acc[4][6];
#pragma unroll
    for (int mt = 0; mt < 4; ++mt)
#pragma unroll
        for (int nt = 0; nt < 6; ++nt) acc[mt][nt] = (f32x4){0.f, 0.f, 0.f, 0.f};

    for (int cc = 0; cc < 3; ++cc) {
#pragma unroll
        for (int dy = -1; dy <= 1; ++dy) {
            const int hh = hrow + dy;
            if (hh < 0 || hh >= HH) continue;         // wave-uniform skip
            // lane's channel slice of row hh: + w*CC picks the pixel
            const unsigned short* xrow =
                xbc + ((size_t)(b * HH + hh) * WW) * CC + cc * 32 + qq * 8;
#pragma unroll
            for (int dx = -1; dx <= 1; ++dx) {
                const int tap = (dy + 1) * 3 + (dx + 1);
                const unsigned short* bsrc = wT2p + (size_t)(tap * 3 + cc) * 6 * 512;
                short8 bf[6];
#pragma unroll
                for (int nt = 0; nt < 6; ++nt)
                    bf[nt] = *(const short8*)(bsrc + nt * 512 + (lrow * 4 + qq) * 8);
                short8 af[4];
#pragma unroll
                for (int mt = 0; mt < 4; ++mt) {
                    const int w = wwbase + mt * 16 + lrow + dx;
                    af[mt] = (w >= 0 && w < WW)
                                 ? *(const short8*)(xrow + (size_t)w * CC)
                                 : (short8){0,0,0,0,0,0,0,0};
                }
#pragma unroll
                for (int nt = 0; nt < 6; ++nt)
#pragma unroll
                    for (int mt = 0; mt < 4; ++mt)
                        acc[mt][nt] = __builtin_amdgcn_mfma_f32_16x16x32_bf16(
                            af[mt], bf[nt], acc[mt][nt], 0, 0, 0);
            }
        }
    }

    const float* g  = (cid == 0) ? gq : (cid == 1) ? gk : gv;
    const float* bt = (cid == 0) ? bq : (cid == 1) ? bk : bv;
    const float* mu = (cid == 0) ? mq : (cid == 1) ? mk : mv;
    const float* var = (cid == 0) ? vq : (cid == 1) ? vk : vv;
    unsigned short* outp = (cid == 0) ? qb : (cid == 1) ? kb : vb;

    // epilogue: C layout col=lane&15, row=(lane>>4)*4+reg
#pragma unroll
    for (int nt = 0; nt < 6; ++nt) {
        const int co = nt * 16 + lrow;
        const float scl = g[co] * rsqrtf(var[co] + EPSF);
        const float sft = bt[co] - mu[co] * scl;
#pragma unroll
        for (int mt = 0; mt < 4; ++mt) {
#pragma unroll
            for (int r = 0; r < 4; ++r) {
                const int row = (wv << 6) + (mt << 4) + (qq << 2) + r;
                const int h = h0 + (row >> 7);
                const int w = row & 127;
                const size_t pix = (size_t)(b * HH + h) * WW + w;
                const float t = acc[mt][nt][r] * scl + sft;
                const float e = __builtin_amdgcn_exp2f(t * -1.442695041f);
                outp[pix * CC + co] = f2bf(__builtin_amdgcn_rcpf(1.0f + e));
            }
        }
    }
}

// ---------------------------------------------------------------------------
// FALLBACK conv (verbatim round-2 proven path): fused cast + LDS staging.
// Used only if ws_size cannot hold the xb buffer.
// ---------------------------------------------------------------------------
__global__ __launch_bounds__(256, 3) void conv_all_lds(
    const float* __restrict__ x1, const float* __restrict__ x2,
    const float* __restrict__ x3, const unsigned short* __restrict__ wT2,
    const float* __restrict__ gq, const float* __restrict__ bq,
    const float* __restrict__ mq, const float* __restrict__ vq,
    const float* __restrict__ gk, const float* __restrict__ bk,
    const float* __restrict__ mk, const float* __restrict__ vk,
    const float* __restrict__ gv, const float* __restrict__ bv,
    const float* __restrict__ mv, const float* __restrict__ vv,
    unsigned short* __restrict__ qb, unsigned short* __restrict__ kb,
    unsigned short* __restrict__ vb)
{
    __shared__ __align__(16) char smem[4 * ROWB];
    const int tid = threadIdx.x;
    const int wv = tid >> 6;
    const int L  = tid & 63;
    const int cid = blockIdx.x >> 9;
    const int blk = blockIdx.x & 511;
    const int b  = blk >> 6;
    const int h0 = (blk & 63) << 1;
    const int hrow = h0 + (wv >> 1);
    const int wwbase = (wv & 1) << 6;
    const int lrow = L & 15;
    const int qq = L >> 4;

    const float* xsrc = (cid == 0) ? x1 : (cid == 1) ? x2 : x3;
    const unsigned short* wT2p = wT2 + (size_t)cid * WELEM;

    const int hst = h0 - 1 + wv;
    const bool stv = (hst >= 0) && (hst < HH);
    const float* xrow = xsrc + (size_t)(b * HH + (stv ? hst : 0)) * WW * CC;
    char* myrow = smem + wv * ROWB;

    f32x4 acc[4][6];
#pragma unroll
    for (int mt = 0; mt < 4; ++mt)
#pragma unroll
        for (int nt = 0; nt < 6; ++nt) acc[mt][nt] = (f32x4){0.f, 0.f, 0.f, 0.f};

    for (int cc = 0; cc < 3; ++cc) {
        __syncthreads();
        if (stv) {
#pragma unroll
            for (int it = 0; it < 9; ++it) {
                const int idx = it * 64 + L;
                if (idx < 520) {
                    const int p = idx >> 2;
                    const int c = idx & 3;
                    const int w = p - 1;
                    short8 o = (short8){0,0,0,0,0,0,0,0};
                    if (w >= 0 && w < WW) {
                        const float* src = xrow + (size_t)w * CC + cc * 32 + c * 8;
                        const float4 a0 = *(const float4*)src;
                        const float4 a1 = *(const float4*)(src + 4);
                        o[0] = (short)f2bf(a0.x); o[1] = (short)f2bf(a0.y);
                        o[2] = (short)f2bf(a0.z); o[3] = (short)f2bf(a0.w);
                        o[4] = (short)f2bf(a1.x); o[5] = (short)f2bf(a1.y);
                        o[6] = (short)f2bf(a1.z); o[7] = (short)f2bf(a1.w);
                    }
                    const int slot = c ^ ((p ^ (p >> 2)) & 3);
                    *(short8*)(myrow + p * 64 + slot * 16) = o;
                }
            }
        }
        __syncthreads();
#pragma unroll
        for (int dy = -1; dy <= 1; ++dy) {
            const int hh = hrow + dy;
            if (hh < 0 || hh >= HH) continue;
            const char* ldsrow = smem + (dy + 1 + (wv >> 1)) * ROWB;
#pragma unroll
            for (int dx = -1; dx <= 1; ++dx) {
                const int tap = (dy + 1) * 3 + (dx + 1);
                const unsigned short* bsrc = wT2p + (size_t)(tap * 3 + cc) * 6 * 512;
                short8 bf[6];
#pragma unroll
                for (int nt = 0; nt < 6; ++nt)
                    bf[nt] = *(const short8*)(bsrc + nt * 512 + (lrow * 4 + qq) * 8);
                short8 af[4];
#pragma unroll
                for (int mt = 0; mt < 4; ++mt) {
                    const int p = wwbase + mt * 16 + lrow + dx + 1;
                    const int slot = qq ^ ((p ^ (p >> 2)) & 3);
                    af[mt] = *(const short8*)(ldsrow + p * 64 + slot * 16);
                }
#pragma unroll
                for (int nt = 0; nt < 6; ++nt)
#pragma unroll
                    for (int mt = 0; mt < 4; ++mt)
                        acc[mt][nt] = __builtin_amdgcn_mfma_f32_16x16x32_bf16(
                            af[mt], bf[nt], acc[mt][nt], 0, 0, 0);
            }
        }
    }

    const float* g  = (cid == 0) ? gq : (cid == 1) ? gk : gv;
    const float* bt = (cid == 0) ? bq : (cid == 1) ? bk : bv;
    const float* mu = (cid == 0) ? mq : (cid == 1) ? mk : mv;
    const float* var = (cid == 0) ? vq : (cid == 1) ? vk : vv;
    unsigned short* outp = (cid == 0) ? qb : (cid == 1) ? kb : vb;

#pragma unroll
    for (int nt = 0; nt < 6; ++nt) {
        const int co = nt * 16 + lrow;
        const float scl = g[co] * rsqrtf(var[co] + EPSF);
        const float sft = bt[co] - mu[co] * scl;
#pragma unroll
        for (int mt = 0; mt < 4; ++mt) {
#pragma unroll
            for (int r = 0; r < 4; ++r) {
                const int row = (wv << 6) + (mt << 4) + (qq << 2) + r;
                const int h = h0 + (row >> 7);
                const int w = row & 127;
                const size_t pix = (size_t)(b * HH + h) * WW + w;
                const float t = acc[mt][nt][r] * scl + sft;
                const float e = __builtin_amdgcn_exp2f(t * -1.442695041f);
                outp[pix * CC + co] = f2bf(__builtin_amdgcn_rcpf(1.0f + e));
            }
        }
    }
}

// ---------------------------------------------------------------------------
// Fused attention sums: per-pixel spatial Tanimoto + per-channel partials,
// one pass over q,k. 1024 blocks x 192 threads; block = 128-pixel slab.
// ---------------------------------------------------------------------------
__global__ __launch_bounds__(192) void qk_att(
    const unsigned short* __restrict__ qb, const unsigned short* __restrict__ kb,
    float* __restrict__ atts, float* __restrict__ part)
{
    __shared__ float pxr[128][37];
    __shared__ float red[16][12][24];
    const int t = threadIdx.x;
    const int g = t / 12;
    const int c8 = t - g * 12;
    const size_t p0 = (size_t)blockIdx.x * 128;

    float s_tpl[8], s_tpp[8], s_tll[8];
#pragma unroll
    for (int j = 0; j < 8; ++j) { s_tpl[j] = 0.f; s_tpp[j] = 0.f; s_tll[j] = 0.f; }

#pragma unroll
    for (int i = 0; i < 8; ++i) {
        const int px = g + i * 16;
        const size_t pe = (p0 + px) * CC + c8 * 8;
        const short8 qv = *(const short8*)(qb + pe);
        const short8 kv = *(const short8*)(kb + pe);
        float ptpl = 0.f, ptpp = 0.f, ptll = 0.f;
#pragma unroll
        for (int j = 0; j < 8; ++j) {
            const float qf = bf2f((unsigned short)qv[j]);
            const float kf = bf2f((unsigned short)kv[j]);
            s_tpl[j] = fmaf(qf, kf, s_tpl[j]);
            s_tpp[j] = fmaf(qf, qf, s_tpp[j]);
            s_tll[j] = fmaf(kf, kf, s_tll[j]);
            ptpl = fmaf(qf, kf, ptpl);
            ptpp = fmaf(qf, qf, ptpp);
            ptll = fmaf(kf, kf, ptll);
        }
        pxr[px][c8 * 3 + 0] = ptpl;
        pxr[px][c8 * 3 + 1] = ptpp;
        pxr[px][c8 * 3 + 2] = ptll;
    }
#pragma unroll
    for (int j = 0; j < 8; ++j) {
        red[g][c8][j]      = s_tpl[j];
        red[g][c8][8 + j]  = s_tpp[j];
        red[g][c8][16 + j] = s_tll[j];
    }
    __syncthreads();

    if (t < 128) {
        float tpl = 0.f, tpp = 0.f, tll = 0.f;
#pragma unroll
        for (int c = 0; c < 12; ++c) {
            tpl += pxr[t][c * 3 + 0];
            tpp += pxr[t][c * 3 + 1];
            tll += pxr[t][c * 3 + 2];
        }
        atts[p0 + t] = ftanimoto(tpl, tpp, tll);
    }

    if (t < CC) {
        const int cg = t >> 3, cj = t & 7;
        float tpl = 0.f, tpp = 0.f, tll = 0.f;
        for (int gg = 0; gg < 16; ++gg) {
            tpl += red[gg][cg][cj];
            tpp += red[gg][cg][8 + cj];
            tll += red[gg][cg][16 + cj];
        }
        const size_t idx = ((size_t)blockIdx.x * CC + t) * 3;
        part[idx + 0] = tpl;
        part[idx + 1] = tpp;
        part[idx + 2] = tll;
    }
}

// ---------------------------------------------------------------------------
// Channel attention stage 2: one wave per (b,c); lane s sums slabs s, s+64.
// ---------------------------------------------------------------------------
__global__ __launch_bounds__(256) void chan_final2(
    const float* __restrict__ part, float* __restrict__ attc)
{
    const int wid = blockIdx.x * 4 + (threadIdx.x >> 6);   // 0..767
    const int lane = threadIdx.x & 63;
    const int b = wid / CC;
    const int c = wid - b * CC;
    const size_t base = (((size_t)b * 128 + lane) * CC + c) * 3;
    const size_t off = (size_t)64 * CC * 3;
    float tpl = part[base + 0] + part[base + off + 0];
    float tpp = part[base + 1] + part[base + off + 1];
    float tll = part[base + 2] + part[base + off + 2];
#pragma unroll
    for (int off2 = 32; off2 > 0; off2 >>= 1) {
        tpl += __shfl_xor(tpl, off2);
        tpp += __shfl_xor(tpp, off2);
        tll += __shfl_xor(tll, off2);
    }
    if (lane == 0) attc[b * CC + c] = ftanimoto(tpl, tpp, tll);
}

// ---------------------------------------------------------------------------
// Final combine: out = bn(0.5*(attc+atts)*v). Reads v bf16, writes fp32.
// ---------------------------------------------------------------------------
__global__ __launch_bounds__(256) void final_combine(
    const unsigned short* __restrict__ vb, const float* __restrict__ atts,
    const float* __restrict__ attc,
    const float* __restrict__ gn, const float* __restrict__ bnb,
    const float* __restrict__ mn, const float* __restrict__ vn,
    float* __restrict__ out)
{
    const int tid = blockIdx.x * 256 + threadIdx.x;   // NPIX*12 jobs
    const int c8 = tid % 12;
    const int pix = tid / 12;
    const int b = pix >> 14;                          // HH*WW = 16384
    const short8 v = *(const short8*)(vb + (size_t)pix * CC + c8 * 8);
    const float as = atts[pix];
    float r[8];
#pragma unroll
    for (int j = 0; j < 8; ++j) {
        const int co = c8 * 8 + j;
        const float nscl = gn[co] * rsqrtf(vn[co] + EPSF);
        const float nsft = bnb[co] - mn[co] * nscl;
        const float att = 0.5f * (attc[b * CC + co] + as);
        r[j] = att * bf2f((unsigned short)v[j]) * nscl + nsft;
    }
    float* dst = out + (size_t)pix * CC + c8 * 8;
    *(float4*)dst = make_float4(r[0], r[1], r[2], r[3]);
    *(float4*)(dst + 4) = make_float4(r[4], r[5], r[6], r[7]);
}

extern "C" void kernel_launch(void* const* d_in, const int* in_sizes, int n_in,
                              void* d_out, int out_size, void* d_ws, size_t ws_size,
                              hipStream_t stream)
{
    const float* x1 = (const float*)d_in[0];
    const float* x2 = (const float*)d_in[1];
    const float* x3 = (const float*)d_in[2];
    const float* wq = (const float*)d_in[3];
    const float* gq = (const float*)d_in[4];
    const float* bq = (const float*)d_in[5];
    const float* mq = (const float*)d_in[6];
    const float* vq = (const float*)d_in[7];
    const float* wk = (const float*)d_in[8];
    const float* gk = (const float*)d_in[9];
    const float* bk = (const float*)d_in[10];
    const float* mk = (const float*)d_in[11];
    const float* vk = (const float*)d_in[12];
    const float* wvw = (const float*)d_in[13];
    const float* gv = (const float*)d_in[14];
    const float* bv = (const float*)d_in[15];
    const float* mv = (const float*)d_in[16];
    const float* vv = (const float*)d_in[17];
    const float* gn = (const float*)d_in[18];
    const float* bnb = (const float*)d_in[19];
    const float* mn = (const float*)d_in[20];
    const float* vn = (const float*)d_in[21];

    // workspace layout: wT2 | xb | vb | atts | part | attc  (~103 MB)
    unsigned short* wT2 = (unsigned short*)d_ws;                  // 3*82944 bf16
    unsigned short* xb = wT2 + (size_t)3 * WELEM;                 // 3*NPIX*96 bf16
    unsigned short* vb = xb + (size_t)3 * NPIX * CC;              // NPIX*96 bf16
    float* atts = (float*)(vb + (size_t)NPIX * CC);               // NPIX fp32
    float* part = atts + NPIX;                                    // 1024*96*3
    float* attc = part + (size_t)1024 * CC * 3;                   // 768

    const size_t need = (size_t)((char*)(attc + 768) - (char*)d_ws);

    unsigned short* qb = (unsigned short*)d_out;
    unsigned short* kb = qb + (size_t)NPIX * CC;

    if (ws_size >= need) {
        precast<<<WBLK + XJOBS / 256, 256, 0, stream>>>(wq, wk, wvw, wT2,
                                                        x1, x2, x3, xb);
        conv_direct<<<1536, 256, 0, stream>>>(xb, wT2,
                                              gq, bq, mq, vq, gk, bk, mk, vk,
                                              gv, bv, mv, vv, qb, kb, vb);
    } else {
        // small-workspace fallback: round-2 proven path (vb right after wT2)
        vb = wT2 + (size_t)3 * WELEM;
        atts = (float*)(vb + (size_t)NPIX * CC);
        part = atts + NPIX;
        attc = part + (size_t)1024 * CC * 3;
        precast<<<WBLK, 256, 0, stream>>>(wq, wk, wvw, wT2, x1, x2, x3, xb);
        conv_all_lds<<<1536, 256, 0, stream>>>(x1, x2, x3, wT2,
                                               gq, bq, mq, vq, gk, bk, mk, vk,
                                               gv, bv, mv, vv, qb, kb, vb);
    }
    qk_att<<<NPIX / 128, 192, 0, stream>>>(qb, kb, atts, part);
    chan_final2<<<192, 256, 0, stream>>>(part, attc);
    final_combine<<<NPIX * 12 / 256, 256, 0, stream>>>(vb, atts, attc,
                                                       gn, bnb, mn, vn,
                                                       (float*)d_out);
}

// Round 4
// 338.695 us; speedup vs baseline: 1.2357x; 1.2357x over previous
//
#include <hip/hip_runtime.h>
#include <hip/hip_bf16.h>
#include <math.h>

#define BB 8
#define HH 128
#define WW 128
#define CC 96
#define NPIX (BB*HH*WW)
#define EPSF 1e-5f
#define FT_SMOOTH_F 1e-5f
#define ROWB 8320                 // fallback path: 130 px x 64 B per LDS row
#define ROWB2 8192                // DMA path: 128 px x 64 B per LDS row
#define WELEM 82944               // 864*96 weight elements per conv
#define WBLK 972                  // precast: weight-repack blocks (3*WELEM/256)
#define XJOBS (3*NPIX*12)         // precast: x-cast jobs (8 floats each)

typedef short short8 __attribute__((ext_vector_type(8)));
typedef float f32x4 __attribute__((ext_vector_type(4)));

__device__ __forceinline__ float ftanimoto(float tpl, float tpp, float tll) {
    float num = tpl + FT_SMOOTH_F;
    float denum = 0.0f;
    float a = 1.0f;
#pragma unroll
    for (int d = 0; d < 5; ++d) {
        float bco = -(2.0f * a - 1.0f);
        denum += 1.0f / (a * (tpp + tll) + bco * tpl + FT_SMOOTH_F);
        a *= 2.0f;
    }
    return num * denum * 0.2f;
}

__device__ __forceinline__ unsigned short f2bf(float f) {
    __hip_bfloat16 h = __float2bfloat16(f);
    return *(unsigned short*)&h;
}

__device__ __forceinline__ float bf2f(unsigned short u) {
    return __uint_as_float((unsigned int)u << 16);
}

// async global->LDS DMA, 16 B per lane; LDS dest = uniform base + lane*16
__device__ __forceinline__ void gload_lds16(const unsigned short* g, char* l) {
    __builtin_amdgcn_global_load_lds(
        (const __attribute__((address_space(1))) unsigned int*)g,
        (__attribute__((address_space(3))) unsigned int*)l, 16, 0, 0);
}

// ---------------------------------------------------------------------------
// precast: ONE dispatch does (a) weight repack (blocks < WBLK) and
// (b) x1..3 fp32 -> bf16 cast into xb (blocks >= WBLK).
// ---------------------------------------------------------------------------
__global__ __launch_bounds__(256) void precast(
    const float* __restrict__ wq, const float* __restrict__ wk,
    const float* __restrict__ wv, unsigned short* __restrict__ wT2,
    const float* __restrict__ x1, const float* __restrict__ x2,
    const float* __restrict__ x3, unsigned short* __restrict__ xb)
{
    if (blockIdx.x < WBLK) {
        const int tid = blockIdx.x * 256 + threadIdx.x;   // < 3*WELEM exactly
        const int cid = tid / WELEM;
        const int o = tid - cid * WELEM;
        const int j = o & 7;
        const int rest = o >> 3;
        const int lq = rest & 63;
        const int lrow = lq >> 2, qq = lq & 3;
        const int tile = rest >> 6;          // (tap*3+cc)*6+nt
        const int nt = tile % 6;
        const int tcc = tile / 6;
        const int cc = tcc % 3, tap = tcc / 3;
        const int ci = cc * 32 + qq * 8 + j;
        const int co = nt * 16 + lrow;
        const float* w = (cid == 0) ? wq : (cid == 1) ? wk : wv;
        wT2[tid] = f2bf(w[(size_t)(tap * CC + ci) * CC + co]);
        return;
    }
    const int tid2 = (blockIdx.x - WBLK) * 256 + threadIdx.x;  // < XJOBS exactly
    const int cid = tid2 / (NPIX * 12);
    const int rem = tid2 - cid * (NPIX * 12);
    const float* xs = (cid == 0) ? x1 : (cid == 1) ? x2 : x3;
    const float4 a0 = *(const float4*)(xs + (size_t)rem * 8);
    const float4 a1 = *(const float4*)(xs + (size_t)rem * 8 + 4);
    short8 o;
    o[0] = (short)f2bf(a0.x); o[1] = (short)f2bf(a0.y);
    o[2] = (short)f2bf(a0.z); o[3] = (short)f2bf(a0.w);
    o[4] = (short)f2bf(a1.x); o[5] = (short)f2bf(a1.y);
    o[6] = (short)f2bf(a1.z); o[7] = (short)f2bf(a1.w);
    *(short8*)(xb + (size_t)cid * NPIX * CC + (size_t)rem * 8) = o;
}

// ---------------------------------------------------------------------------
// Conv with double-buffered global_load_lds DMA staging (T3/T4 pattern):
// stage(cc+1) is ISSUED before compute(cc); the vmcnt(0) drain emitted by
// __syncthreads() lands after 216 MFMAs, so HBM latency hides under compute.
// LDS = 2 buf x 4 rows x 128 px x 64 B = 64 KB (boundary px w=-1/128 become
// zero fragments in compute). Swizzled layout achieved by pre-swizzling the
// per-lane GLOBAL source address (DMA dest must be linear).
// ---------------------------------------------------------------------------
__global__ __launch_bounds__(256, 2) void conv_bf16(
    const unsigned short* __restrict__ xb, const unsigned short* __restrict__ wT2,
    const float* __restrict__ gq, const float* __restrict__ bq,
    const float* __restrict__ mq, const float* __restrict__ vq,
    const float* __restrict__ gk, const float* __restrict__ bk,
    const float* __restrict__ mk, const float* __restrict__ vk,
    const float* __restrict__ gv, const float* __restrict__ bv,
    const float* __restrict__ mv, const float* __restrict__ vv,
    unsigned short* __restrict__ qb, unsigned short* __restrict__ kb,
    unsigned short* __restrict__ vb)
{
    __shared__ __align__(16) char smem[2 * 4 * ROWB2];   // 65,536 B
    const int tid = threadIdx.x;
    const int wvi = tid >> 6;
    const int L  = tid & 63;
    const int cid = blockIdx.x >> 9;                  // 0:q 1:k 2:v
    const int blk = blockIdx.x & 511;
    const int b  = blk >> 6;
    const int h0 = (blk & 63) << 1;
    const int hrow = h0 + (wvi >> 1);
    const int wwbase = (wvi & 1) << 6;
    const int lrow = L & 15;
    const int qq = L >> 4;

    const unsigned short* xbc = xb + (size_t)cid * NPIX * CC;
    const unsigned short* wT2p = wT2 + (size_t)cid * WELEM;

    // staging: wave wvi owns LDS row wvi <- image row h0-1+wvi
    const int hst = h0 - 1 + wvi;
    const bool stv = (hst >= 0) && (hst < HH);
    const unsigned short* xrow = xbc + (size_t)(b * HH + (stv ? hst : 0)) * WW * CC;

    f32x4 acc[4][6];
#pragma unroll
    for (int mt = 0; mt < 4; ++mt)
#pragma unroll
        for (int nt = 0; nt < 6; ++nt) acc[mt][nt] = (f32x4){0.f, 0.f, 0.f, 0.f};

    // lane's DMA source pre-swizzle: pixel w = it*16 + (L>>2), dest slot L&3,
    // so source chunk c = (L&3) ^ ((w ^ (w>>2)) & 3). Dest is linear.
#define STAGE(buf, ccv) do { if (stv) { _Pragma("unroll") \
    for (int it = 0; it < 8; ++it) { \
        const int w = it * 16 + (L >> 2); \
        const int c = (L & 3) ^ ((w ^ (w >> 2)) & 3); \
        gload_lds16(xrow + (size_t)w * CC + (ccv) * 32 + c * 8, \
                    smem + (buf) * 4 * ROWB2 + wvi * ROWB2 + it * 1024); \
    } } } while (0)

#define COMPUTE(buf, ccv) do { _Pragma("unroll") \
    for (int dy = -1; dy <= 1; ++dy) { \
        const int hh = hrow + dy; \
        if (hh < 0 || hh >= HH) continue; \
        const char* ldsrow = smem + (buf) * 4 * ROWB2 + (dy + 1 + (wvi >> 1)) * ROWB2; \
        _Pragma("unroll") \
        for (int dx = -1; dx <= 1; ++dx) { \
            const int tap = (dy + 1) * 3 + (dx + 1); \
            const unsigned short* bsrc = wT2p + (size_t)(tap * 3 + (ccv)) * 6 * 512; \
            short8 bfr[6]; \
            _Pragma("unroll") \
            for (int nt = 0; nt < 6; ++nt) \
                bfr[nt] = *(const short8*)(bsrc + nt * 512 + (lrow * 4 + qq) * 8); \
            short8 afr[4]; \
            _Pragma("unroll") \
            for (int mt = 0; mt < 4; ++mt) { \
                const int w2 = wwbase + mt * 16 + lrow + dx; \
                if (w2 >= 0 && w2 < WW) { \
                    const int slot = qq ^ ((w2 ^ (w2 >> 2)) & 3); \
                    afr[mt] = *(const short8*)(ldsrow + w2 * 64 + slot * 16); \
                } else { \
                    afr[mt] = (short8){0,0,0,0,0,0,0,0}; \
                } \
            } \
            _Pragma("unroll") \
            for (int nt = 0; nt < 6; ++nt) \
                _Pragma("unroll") \
                for (int mt = 0; mt < 4; ++mt) \
                    acc[mt][nt] = __builtin_amdgcn_mfma_f32_16x16x32_bf16( \
                        afr[mt], bfr[nt], acc[mt][nt], 0, 0, 0); \
        } } } while (0)

    STAGE(0, 0);
    __syncthreads();            // drains vmcnt(0): buf0 ready
    STAGE(1, 1);                // DMA in flight across compute(0)
    COMPUTE(0, 0);
    __syncthreads();            // buf1 ready; all waves done reading buf0
    STAGE(0, 2);                // DMA in flight across compute(1)
    COMPUTE(1, 1);
    __syncthreads();            // buf0(cc2) ready
    COMPUTE(0, 2);

#undef STAGE
#undef COMPUTE

    const float* g  = (cid == 0) ? gq : (cid == 1) ? gk : gv;
    const float* bt = (cid == 0) ? bq : (cid == 1) ? bk : bv;
    const float* mu = (cid == 0) ? mq : (cid == 1) ? mk : mv;
    const float* var = (cid == 0) ? vq : (cid == 1) ? vk : vv;
    unsigned short* outp = (cid == 0) ? qb : (cid == 1) ? kb : vb;

    // epilogue: C layout col=lane&15, row=(lane>>4)*4+reg
#pragma unroll
    for (int nt = 0; nt < 6; ++nt) {
        const int co = nt * 16 + lrow;
        const float scl = g[co] * rsqrtf(var[co] + EPSF);
        const float sft = bt[co] - mu[co] * scl;
#pragma unroll
        for (int mt = 0; mt < 4; ++mt) {
#pragma unroll
            for (int r = 0; r < 4; ++r) {
                const int row = (wvi << 6) + (mt << 4) + (qq << 2) + r;
                const int h = h0 + (row >> 7);
                const int w = row & 127;
                const size_t pix = (size_t)(b * HH + h) * WW + w;
                const float t = acc[mt][nt][r] * scl + sft;
                const float e = __builtin_amdgcn_exp2f(t * -1.442695041f);
                outp[pix * CC + co] = f2bf(__builtin_amdgcn_rcpf(1.0f + e));
            }
        }
    }
}

// ---------------------------------------------------------------------------
// FALLBACK conv (verbatim round-2 proven path): fused cast + LDS staging.
// Used only if ws_size cannot hold the xb buffer.
// ---------------------------------------------------------------------------
__global__ __launch_bounds__(256, 3) void conv_all_lds(
    const float* __restrict__ x1, const float* __restrict__ x2,
    const float* __restrict__ x3, const unsigned short* __restrict__ wT2,
    const float* __restrict__ gq, const float* __restrict__ bq,
    const float* __restrict__ mq, const float* __restrict__ vq,
    const float* __restrict__ gk, const float* __restrict__ bk,
    const float* __restrict__ mk, const float* __restrict__ vk,
    const float* __restrict__ gv, const float* __restrict__ bv,
    const float* __restrict__ mv, const float* __restrict__ vv,
    unsigned short* __restrict__ qb, unsigned short* __restrict__ kb,
    unsigned short* __restrict__ vb)
{
    __shared__ __align__(16) char smem[4 * ROWB];
    const int tid = threadIdx.x;
    const int wv = tid >> 6;
    const int L  = tid & 63;
    const int cid = blockIdx.x >> 9;
    const int blk = blockIdx.x & 511;
    const int b  = blk >> 6;
    const int h0 = (blk & 63) << 1;
    const int hrow = h0 + (wv >> 1);
    const int wwbase = (wv & 1) << 6;
    const int lrow = L & 15;
    const int qq = L >> 4;

    const float* xsrc = (cid == 0) ? x1 : (cid == 1) ? x2 : x3;
    const unsigned short* wT2p = wT2 + (size_t)cid * WELEM;

    const int hst = h0 - 1 + wv;
    const bool stv = (hst >= 0) && (hst < HH);
    const float* xrow = xsrc + (size_t)(b * HH + (stv ? hst : 0)) * WW * CC;
    char* myrow = smem + wv * ROWB;

    f32x4 acc[4][6];
#pragma unroll
    for (int mt = 0; mt < 4; ++mt)
#pragma unroll
        for (int nt = 0; nt < 6; ++nt) acc[mt][nt] = (f32x4){0.f, 0.f, 0.f, 0.f};

    for (int cc = 0; cc < 3; ++cc) {
        __syncthreads();
        if (stv) {
#pragma unroll
            for (int it = 0; it < 9; ++it) {
                const int idx = it * 64 + L;
                if (idx < 520) {
                    const int p = idx >> 2;
                    const int c = idx & 3;
                    const int w = p - 1;
                    short8 o = (short8){0,0,0,0,0,0,0,0};
                    if (w >= 0 && w < WW) {
                        const float* src = xrow + (size_t)w * CC + cc * 32 + c * 8;
                        const float4 a0 = *(const float4*)src;
                        const float4 a1 = *(const float4*)(src + 4);
                        o[0] = (short)f2bf(a0.x); o[1] = (short)f2bf(a0.y);
                        o[2] = (short)f2bf(a0.z); o[3] = (short)f2bf(a0.w);
                        o[4] = (short)f2bf(a1.x); o[5] = (short)f2bf(a1.y);
                        o[6] = (short)f2bf(a1.z); o[7] = (short)f2bf(a1.w);
                    }
                    const int slot = c ^ ((p ^ (p >> 2)) & 3);
                    *(short8*)(myrow + p * 64 + slot * 16) = o;
                }
            }
        }
        __syncthreads();
#pragma unroll
        for (int dy = -1; dy <= 1; ++dy) {
            const int hh = hrow + dy;
            if (hh < 0 || hh >= HH) continue;
            const char* ldsrow = smem + (dy + 1 + (wv >> 1)) * ROWB;
#pragma unroll
            for (int dx = -1; dx <= 1; ++dx) {
                const int tap = (dy + 1) * 3 + (dx + 1);
                const unsigned short* bsrc = wT2p + (size_t)(tap * 3 + cc) * 6 * 512;
                short8 bf[6];
#pragma unroll
                for (int nt = 0; nt < 6; ++nt)
                    bf[nt] = *(const short8*)(bsrc + nt * 512 + (lrow * 4 + qq) * 8);
                short8 af[4];
#pragma unroll
                for (int mt = 0; mt < 4; ++mt) {
                    const int p = wwbase + mt * 16 + lrow + dx + 1;
                    const int slot = qq ^ ((p ^ (p >> 2)) & 3);
                    af[mt] = *(const short8*)(ldsrow + p * 64 + slot * 16);
                }
#pragma unroll
                for (int nt = 0; nt < 6; ++nt)
#pragma unroll
                    for (int mt = 0; mt < 4; ++mt)
                        acc[mt][nt] = __builtin_amdgcn_mfma_f32_16x16x32_bf16(
                            af[mt], bf[nt], acc[mt][nt], 0, 0, 0);
            }
        }
    }

    const float* g  = (cid == 0) ? gq : (cid == 1) ? gk : gv;
    const float* bt = (cid == 0) ? bq : (cid == 1) ? bk : bv;
    const float* mu = (cid == 0) ? mq : (cid == 1) ? mk : mv;
    const float* var = (cid == 0) ? vq : (cid == 1) ? vk : vv;
    unsigned short* outp = (cid == 0) ? qb : (cid == 1) ? kb : vb;

#pragma unroll
    for (int nt = 0; nt < 6; ++nt) {
        const int co = nt * 16 + lrow;
        const float scl = g[co] * rsqrtf(var[co] + EPSF);
        const float sft = bt[co] - mu[co] * scl;
#pragma unroll
        for (int mt = 0; mt < 4; ++mt) {
#pragma unroll
            for (int r = 0; r < 4; ++r) {
                const int row = (wv << 6) + (mt << 4) + (qq << 2) + r;
                const int h = h0 + (row >> 7);
                const int w = row & 127;
                const size_t pix = (size_t)(b * HH + h) * WW + w;
                const float t = acc[mt][nt][r] * scl + sft;
                const float e = __builtin_amdgcn_exp2f(t * -1.442695041f);
                outp[pix * CC + co] = f2bf(__builtin_amdgcn_rcpf(1.0f + e));
            }
        }
    }
}

// ---------------------------------------------------------------------------
// Fused attention sums: per-pixel spatial Tanimoto + per-channel partials,
// one pass over q,k. 1024 blocks x 192 threads; block = 128-pixel slab.
// ---------------------------------------------------------------------------
__global__ __launch_bounds__(192) void qk_att(
    const unsigned short* __restrict__ qb, const unsigned short* __restrict__ kb,
    float* __restrict__ atts, float* __restrict__ part)
{
    __shared__ float pxr[128][37];
    __shared__ float red[16][12][24];
    const int t = threadIdx.x;
    const int g = t / 12;
    const int c8 = t - g * 12;
    const size_t p0 = (size_t)blockIdx.x * 128;

    float s_tpl[8], s_tpp[8], s_tll[8];
#pragma unroll
    for (int j = 0; j < 8; ++j) { s_tpl[j] = 0.f; s_tpp[j] = 0.f; s_tll[j] = 0.f; }

#pragma unroll
    for (int i = 0; i < 8; ++i) {
        const int px = g + i * 16;
        const size_t pe = (p0 + px) * CC + c8 * 8;
        const short8 qv = *(const short8*)(qb + pe);
        const short8 kv = *(const short8*)(kb + pe);
        float ptpl = 0.f, ptpp = 0.f, ptll = 0.f;
#pragma unroll
        for (int j = 0; j < 8; ++j) {
            const float qf = bf2f((unsigned short)qv[j]);
            const float kf = bf2f((unsigned short)kv[j]);
            s_tpl[j] = fmaf(qf, kf, s_tpl[j]);
            s_tpp[j] = fmaf(qf, qf, s_tpp[j]);
            s_tll[j] = fmaf(kf, kf, s_tll[j]);
            ptpl = fmaf(qf, kf, ptpl);
            ptpp = fmaf(qf, qf, ptpp);
            ptll = fmaf(kf, kf, ptll);
        }
        pxr[px][c8 * 3 + 0] = ptpl;
        pxr[px][c8 * 3 + 1] = ptpp;
        pxr[px][c8 * 3 + 2] = ptll;
    }
#pragma unroll
    for (int j = 0; j < 8; ++j) {
        red[g][c8][j]      = s_tpl[j];
        red[g][c8][8 + j]  = s_tpp[j];
        red[g][c8][16 + j] = s_tll[j];
    }
    __syncthreads();

    if (t < 128) {
        float tpl = 0.f, tpp = 0.f, tll = 0.f;
#pragma unroll
        for (int c = 0; c < 12; ++c) {
            tpl += pxr[t][c * 3 + 0];
            tpp += pxr[t][c * 3 + 1];
            tll += pxr[t][c * 3 + 2];
        }
        atts[p0 + t] = ftanimoto(tpl, tpp, tll);
    }

    if (t < CC) {
        const int cg = t >> 3, cj = t & 7;
        float tpl = 0.f, tpp = 0.f, tll = 0.f;
        for (int gg = 0; gg < 16; ++gg) {
            tpl += red[gg][cg][cj];
            tpp += red[gg][cg][8 + cj];
            tll += red[gg][cg][16 + cj];
        }
        const size_t idx = ((size_t)blockIdx.x * CC + t) * 3;
        part[idx + 0] = tpl;
        part[idx + 1] = tpp;
        part[idx + 2] = tll;
    }
}

// ---------------------------------------------------------------------------
// Channel attention stage 2: one wave per (b,c); lane s sums slabs s, s+64.
// ---------------------------------------------------------------------------
__global__ __launch_bounds__(256) void chan_final2(
    const float* __restrict__ part, float* __restrict__ attc)
{
    const int wid = blockIdx.x * 4 + (threadIdx.x >> 6);   // 0..767
    const int lane = threadIdx.x & 63;
    const int b = wid / CC;
    const int c = wid - b * CC;
    const size_t base = (((size_t)b * 128 + lane) * CC + c) * 3;
    const size_t off = (size_t)64 * CC * 3;
    float tpl = part[base + 0] + part[base + off + 0];
    float tpp = part[base + 1] + part[base + off + 1];
    float tll = part[base + 2] + part[base + off + 2];
#pragma unroll
    for (int off2 = 32; off2 > 0; off2 >>= 1) {
        tpl += __shfl_xor(tpl, off2);
        tpp += __shfl_xor(tpp, off2);
        tll += __shfl_xor(tll, off2);
    }
    if (lane == 0) attc[b * CC + c] = ftanimoto(tpl, tpp, tll);
}

// ---------------------------------------------------------------------------
// Final combine: out = bn(0.5*(attc+atts)*v). Reads v bf16, writes fp32.
// ---------------------------------------------------------------------------
__global__ __launch_bounds__(256) void final_combine(
    const unsigned short* __restrict__ vb, const float* __restrict__ atts,
    const float* __restrict__ attc,
    const float* __restrict__ gn, const float* __restrict__ bnb,
    const float* __restrict__ mn, const float* __restrict__ vn,
    float* __restrict__ out)
{
    const int tid = blockIdx.x * 256 + threadIdx.x;   // NPIX*12 jobs
    const int c8 = tid % 12;
    const int pix = tid / 12;
    const int b = pix >> 14;                          // HH*WW = 16384
    const short8 v = *(const short8*)(vb + (size_t)pix * CC + c8 * 8);
    const float as = atts[pix];
    float r[8];
#pragma unroll
    for (int j = 0; j < 8; ++j) {
        const int co = c8 * 8 + j;
        const float nscl = gn[co] * rsqrtf(vn[co] + EPSF);
        const float nsft = bnb[co] - mn[co] * nscl;
        const float att = 0.5f * (attc[b * CC + co] + as);
        r[j] = att * bf2f((unsigned short)v[j]) * nscl + nsft;
    }
    float* dst = out + (size_t)pix * CC + c8 * 8;
    *(float4*)dst = make_float4(r[0], r[1], r[2], r[3]);
    *(float4*)(dst + 4) = make_float4(r[4], r[5], r[6], r[7]);
}

extern "C" void kernel_launch(void* const* d_in, const int* in_sizes, int n_in,
                              void* d_out, int out_size, void* d_ws, size_t ws_size,
                              hipStream_t stream)
{
    const float* x1 = (const float*)d_in[0];
    const float* x2 = (const float*)d_in[1];
    const float* x3 = (const float*)d_in[2];
    const float* wq = (const float*)d_in[3];
    const float* gq = (const float*)d_in[4];
    const float* bq = (const float*)d_in[5];
    const float* mq = (const float*)d_in[6];
    const float* vq = (const float*)d_in[7];
    const float* wk = (const float*)d_in[8];
    const float* gk = (const float*)d_in[9];
    const float* bk = (const float*)d_in[10];
    const float* mk = (const float*)d_in[11];
    const float* vk = (const float*)d_in[12];
    const float* wvw = (const float*)d_in[13];
    const float* gv = (const float*)d_in[14];
    const float* bv = (const float*)d_in[15];
    const float* mv = (const float*)d_in[16];
    const float* vv = (const float*)d_in[17];
    const float* gn = (const float*)d_in[18];
    const float* bnb = (const float*)d_in[19];
    const float* mn = (const float*)d_in[20];
    const float* vn = (const float*)d_in[21];

    // workspace layout: wT2 | xb | vb | atts | part | attc  (~103 MB)
    unsigned short* wT2 = (unsigned short*)d_ws;                  // 3*82944 bf16
    unsigned short* xb = wT2 + (size_t)3 * WELEM;                 // 3*NPIX*96 bf16
    unsigned short* vb = xb + (size_t)3 * NPIX * CC;              // NPIX*96 bf16
    float* atts = (float*)(vb + (size_t)NPIX * CC);               // NPIX fp32
    float* part = atts + NPIX;                                    // 1024*96*3
    float* attc = part + (size_t)1024 * CC * 3;                   // 768

    const size_t need = (size_t)((char*)(attc + 768) - (char*)d_ws);

    unsigned short* qb = (unsigned short*)d_out;
    unsigned short* kb = qb + (size_t)NPIX * CC;

    if (ws_size >= need) {
        precast<<<WBLK + XJOBS / 256, 256, 0, stream>>>(wq, wk, wvw, wT2,
                                                        x1, x2, x3, xb);
        conv_bf16<<<1536, 256, 0, stream>>>(xb, wT2,
                                            gq, bq, mq, vq, gk, bk, mk, vk,
                                            gv, bv, mv, vv, qb, kb, vb);
    } else {
        // small-workspace fallback: round-2 proven path (vb right after wT2)
        vb = wT2 + (size_t)3 * WELEM;
        atts = (float*)(vb + (size_t)NPIX * CC);
        part = atts + NPIX;
        attc = part + (size_t)1024 * CC * 3;
        precast<<<WBLK, 256, 0, stream>>>(wq, wk, wvw, wT2, x1, x2, x3, xb);
        conv_all_lds<<<1536, 256, 0, stream>>>(x1, x2, x3, wT2,
                                               gq, bq, mq, vq, gk, bk, mk, vk,
                                               gv, bv, mv, vv, qb, kb, vb);
    }
    qk_att<<<NPIX / 128, 192, 0, stream>>>(qb, kb, atts, part);
    chan_final2<<<192, 256, 0, stream>>>(part, attc);
    final_combine<<<NPIX * 12 / 256, 256, 0, stream>>>(vb, atts, attc,
                                                       gn, bnb, mn, vn,
                                                       (float*)d_out);
}